// Round 1
// baseline (438.281 us; speedup 1.0000x reference)
//
#include <hip/hip_runtime.h>
#include <math.h>

#define BQn 2
#define QN 13294
#define SN 13294
#define NH 8
#define DH 32
#define DM 256

// ---------------------------------------------------------------------------
// Tiled fp32 GEMM: C[M,N] = A[M,256] @ W[256,N] + bias[N]
// MODE 0: row-major C[M,N]
// MODE 1: value layout: row=(b*S+s), col=(h*32+dh) -> C[b][h][s][dh]
// ---------------------------------------------------------------------------
template<int N, int MODE>
__global__ __launch_bounds__(256) void gemm_bias(
    const float* __restrict__ A, const float* __restrict__ W,
    const float* __restrict__ bias, float* __restrict__ C, int M)
{
    __shared__ float As[16][65];
    __shared__ float Bs[16][64];
    const int tid = threadIdx.x;
    const int tx = tid & 15, ty = tid >> 4;
    const int row0 = blockIdx.y * 64, col0 = blockIdx.x * 64;
    const int ar = tid >> 2, ac = (tid & 3) << 2;   // A tile: 64 rows x 16 cols
    const int br = tid >> 4, bc = (tid & 15) << 2;  // B tile: 16 rows x 64 cols
    float acc[4][4] = {};

    for (int k0 = 0; k0 < DM; k0 += 16) {
        float4 av = make_float4(0.f, 0.f, 0.f, 0.f);
        const int arow = row0 + ar;
        if (arow < M) av = *(const float4*)(A + (size_t)arow * DM + k0 + ac);
        As[ac + 0][ar] = av.x; As[ac + 1][ar] = av.y;
        As[ac + 2][ar] = av.z; As[ac + 3][ar] = av.w;
        *(float4*)(&Bs[br][bc]) =
            *(const float4*)(W + (size_t)(k0 + br) * N + col0 + bc);
        __syncthreads();
        #pragma unroll
        for (int kk = 0; kk < 16; ++kk) {
            float a[4], b[4];
            #pragma unroll
            for (int i = 0; i < 4; ++i) a[i] = As[kk][ty * 4 + i];
            #pragma unroll
            for (int j = 0; j < 4; ++j) b[j] = Bs[kk][tx * 4 + j];
            #pragma unroll
            for (int i = 0; i < 4; ++i)
                #pragma unroll
                for (int j = 0; j < 4; ++j)
                    acc[i][j] = fmaf(a[i], b[j], acc[i][j]);
        }
        __syncthreads();
    }

    #pragma unroll
    for (int i = 0; i < 4; ++i) {
        const int row = row0 + ty * 4 + i;
        if (row >= M) continue;
        #pragma unroll
        for (int j = 0; j < 4; ++j) {
            const int col = col0 + tx * 4 + j;
            const float v = acc[i][j] + bias[col];
            if (MODE == 0) {
                C[(size_t)row * N + col] = v;
            } else {
                const int b = row / SN, s = row - b * SN;
                const int h = col >> 5, dh = col & 31;
                C[(((size_t)b * NH + h) * SN + s) * DH + dh] = v;
            }
        }
    }
}

// ---------------------------------------------------------------------------
// Deformable sampling: 1 thread per (b,q,h). In-register softmax over 16
// logits (writes aw output), then 4 levels x 4 points bilinear gather from
// value[B][H][S][32], weighted accumulate into 32 channels.
// ---------------------------------------------------------------------------
__global__ __launch_bounds__(256) void ms_sample(
    const float* __restrict__ value,   // [B,H,S,32]
    const float* __restrict__ off,     // [B,Q,256]  (h,l,p,2)
    const float* __restrict__ awpre,   // [B,Q,128]  (h,l*p)
    const float* __restrict__ refp,    // [B,Q,4,2]
    float* __restrict__ outh,          // [B,Q,256]  (h*32+dh)
    float* __restrict__ awout)         // [B,Q,128]
{
    const int t = blockIdx.x * 256 + threadIdx.x;
    if (t >= BQn * QN * NH) return;
    const int h  = t & 7;
    const int bq = t >> 3;
    const int b  = bq / QN;

    // ---- softmax over 16 attention logits ----
    float lg[16];
    {
        const float4* ap = (const float4*)(awpre + (size_t)bq * 128 + h * 16);
        #pragma unroll
        for (int i = 0; i < 4; ++i) {
            float4 v = ap[i];
            lg[4*i] = v.x; lg[4*i+1] = v.y; lg[4*i+2] = v.z; lg[4*i+3] = v.w;
        }
    }
    float mx = lg[0];
    #pragma unroll
    for (int i = 1; i < 16; ++i) mx = fmaxf(mx, lg[i]);
    float sum = 0.f;
    #pragma unroll
    for (int i = 0; i < 16; ++i) { lg[i] = expf(lg[i] - mx); sum += lg[i]; }
    const float inv = 1.f / sum;
    #pragma unroll
    for (int i = 0; i < 16; ++i) lg[i] *= inv;
    {
        float4* a4 = (float4*)(awout + (size_t)bq * 128 + h * 16);
        #pragma unroll
        for (int i = 0; i < 4; ++i)
            a4[i] = make_float4(lg[4*i], lg[4*i+1], lg[4*i+2], lg[4*i+3]);
    }

    // ---- offsets ----
    float ofs[32];
    {
        const float4* op = (const float4*)(off + (size_t)bq * 256 + h * 32);
        #pragma unroll
        for (int i = 0; i < 8; ++i) {
            float4 v = op[i];
            ofs[4*i] = v.x; ofs[4*i+1] = v.y; ofs[4*i+2] = v.z; ofs[4*i+3] = v.w;
        }
    }

    const int lw[4]  = {100, 50, 25, 13};
    const int lhh[4] = {100, 50, 25, 13};
    const int lst[4] = {0, 10000, 12500, 13125};

    float acc[32] = {};
    const float* ref = refp + (size_t)bq * 8;

    #pragma unroll
    for (int l = 0; l < 4; ++l) {
        const float rx = ref[l * 2 + 0], ry = ref[l * 2 + 1];
        const int w = lw[l], hh = lhh[l];
        const float fw = (float)w, fh = (float)hh;
        const float* vbase = value + (((size_t)b * NH + h) * SN + lst[l]) * DH;
        #pragma unroll
        for (int p = 0; p < 4; ++p) {
            const float ox = ofs[l * 8 + p * 2 + 0];
            const float oy = ofs[l * 8 + p * 2 + 1];
            const float locx = rx + ox / fw;
            const float locy = ry + oy / fh;
            const float x = locx * fw - 0.5f;
            const float y = locy * fh - 0.5f;
            const float x0f = floorf(x), y0f = floorf(y);
            const int x0 = (int)x0f, y0 = (int)y0f;
            const float wx1 = x - x0f, wx0 = 1.f - wx1;
            const float wy1 = y - y0f, wy0 = 1.f - wy1;
            const float wt = lg[l * 4 + p];

            auto corner = [&](int xi, int yi, float cw) {
                if (xi < 0 || xi >= w || yi < 0 || yi >= hh) return;
                const float wgt = cw * wt;
                const float4* vp =
                    (const float4*)(vbase + (size_t)(yi * w + xi) * DH);
                #pragma unroll
                for (int r = 0; r < 8; ++r) {
                    float4 v = vp[r];
                    acc[r*4+0] = fmaf(wgt, v.x, acc[r*4+0]);
                    acc[r*4+1] = fmaf(wgt, v.y, acc[r*4+1]);
                    acc[r*4+2] = fmaf(wgt, v.z, acc[r*4+2]);
                    acc[r*4+3] = fmaf(wgt, v.w, acc[r*4+3]);
                }
            };
            corner(x0,     y0,     wx0 * wy0);
            corner(x0 + 1, y0,     wx1 * wy0);
            corner(x0,     y0 + 1, wx0 * wy1);
            corner(x0 + 1, y0 + 1, wx1 * wy1);
        }
    }

    float4* o4 = (float4*)(outh + (size_t)bq * 256 + h * 32);
    #pragma unroll
    for (int r = 0; r < 8; ++r)
        o4[r] = make_float4(acc[r*4+0], acc[r*4+1], acc[r*4+2], acc[r*4+3]);
}

// ---------------------------------------------------------------------------
extern "C" void kernel_launch(void* const* d_in, const int* in_sizes, int n_in,
                              void* d_out, int out_size, void* d_ws, size_t ws_size,
                              hipStream_t stream) {
    const float* hs   = (const float*)d_in[0];
    const float* enc  = (const float*)d_in[1];
    const float* refp = (const float*)d_in[2];
    const float* Wv   = (const float*)d_in[3];
    const float* bv   = (const float*)d_in[4];
    const float* Woff = (const float*)d_in[5];
    const float* boff = (const float*)d_in[6];
    const float* Wa   = (const float*)d_in[7];
    const float* ba   = (const float*)d_in[8];
    const float* Wout = (const float*)d_in[9];
    const float* bout = (const float*)d_in[10];

    float* out    = (float*)d_out;
    float* aw_out = out + (size_t)BQn * QN * 256;

    float* ws    = (float*)d_ws;
    float* value = ws;                                    // B*H*S*32
    float* offb  = value + (size_t)BQn * NH * SN * DH;    // B*Q*256
    float* awpre = offb  + (size_t)BQn * QN * 256;        // B*Q*128
    float* outh  = awpre + (size_t)BQn * QN * 128;        // B*Q*256

    const int M = BQn * SN;                               // 26588
    const dim3 blk(256);
    const int my = (M + 63) / 64;

    gemm_bias<256, 1><<<dim3(4, my), blk, 0, stream>>>(enc,  Wv,   bv,   value, M);
    gemm_bias<256, 0><<<dim3(4, my), blk, 0, stream>>>(hs,   Woff, boff, offb,  M);
    gemm_bias<128, 0><<<dim3(2, my), blk, 0, stream>>>(hs,   Wa,   ba,   awpre, M);

    const int nt = BQn * QN * NH;
    ms_sample<<<(nt + 255) / 256, blk, 0, stream>>>(value, offb, awpre, refp,
                                                    outh, aw_out);

    gemm_bias<256, 0><<<dim3(4, my), blk, 0, stream>>>(outh, Wout, bout, out, M);
}

// Round 2
// 308.332 us; speedup vs baseline: 1.4215x; 1.4215x over previous
//
#include <hip/hip_runtime.h>
#include <math.h>

#define BQn 2
#define QN 13294
#define SN 13294
#define NH 8
#define DH 32
#define DM 256

// ---------------------------------------------------------------------------
// Tiled fp32 GEMM: C[M,N] = A[M,256] @ W[256,N] + bias[N]
// MODE 0: row-major C[M,N]
// MODE 1: value layout: row=(b*S+s), col=(h*32+dh) -> C[b][h][s][dh]
// ---------------------------------------------------------------------------
template<int N, int MODE>
__global__ __launch_bounds__(256) void gemm_bias(
    const float* __restrict__ A, const float* __restrict__ W,
    const float* __restrict__ bias, float* __restrict__ C, int M)
{
    __shared__ float As[16][65];
    __shared__ float Bs[16][64];
    const int tid = threadIdx.x;
    const int tx = tid & 15, ty = tid >> 4;
    const int row0 = blockIdx.y * 64, col0 = blockIdx.x * 64;
    const int ar = tid >> 2, ac = (tid & 3) << 2;   // A tile: 64 rows x 16 cols
    const int br = tid >> 4, bc = (tid & 15) << 2;  // B tile: 16 rows x 64 cols
    float acc[4][4] = {};

    for (int k0 = 0; k0 < DM; k0 += 16) {
        float4 av = make_float4(0.f, 0.f, 0.f, 0.f);
        const int arow = row0 + ar;
        if (arow < M) av = *(const float4*)(A + (size_t)arow * DM + k0 + ac);
        As[ac + 0][ar] = av.x; As[ac + 1][ar] = av.y;
        As[ac + 2][ar] = av.z; As[ac + 3][ar] = av.w;
        *(float4*)(&Bs[br][bc]) =
            *(const float4*)(W + (size_t)(k0 + br) * N + col0 + bc);
        __syncthreads();
        #pragma unroll
        for (int kk = 0; kk < 16; ++kk) {
            float a[4], b[4];
            #pragma unroll
            for (int i = 0; i < 4; ++i) a[i] = As[kk][ty * 4 + i];
            #pragma unroll
            for (int j = 0; j < 4; ++j) b[j] = Bs[kk][tx * 4 + j];
            #pragma unroll
            for (int i = 0; i < 4; ++i)
                #pragma unroll
                for (int j = 0; j < 4; ++j)
                    acc[i][j] = fmaf(a[i], b[j], acc[i][j]);
        }
        __syncthreads();
    }

    #pragma unroll
    for (int i = 0; i < 4; ++i) {
        const int row = row0 + ty * 4 + i;
        if (row >= M) continue;
        #pragma unroll
        for (int j = 0; j < 4; ++j) {
            const int col = col0 + tx * 4 + j;
            const float v = acc[i][j] + bias[col];
            if (MODE == 0) {
                C[(size_t)row * N + col] = v;
            } else {
                const int b = row / SN, s = row - b * SN;
                const int h = col >> 5, dh = col & 31;
                C[(((size_t)b * NH + h) * SN + s) * DH + dh] = v;
            }
        }
    }
}

// ---------------------------------------------------------------------------
// Deformable sampling v2: 8 lanes per (b,q,h); lane lc owns channels
// [4*lc, 4*lc+4) and (level,point) pairs lp = 2*lc, 2*lc+1.
// Softmax group-reduced over 8 lanes; per-point coords/weights broadcast
// via __shfl (compile-time slot select). Gathers are coalesced: the 8 lanes
// of a group read one contiguous 128B-aligned segment per corner.
// ---------------------------------------------------------------------------
__global__ __launch_bounds__(256) void ms_sample(
    const float* __restrict__ value,   // [B,H,S,32]
    const float* __restrict__ off,     // [B,Q,256]  (h,l,p,2)
    const float* __restrict__ awpre,   // [B,Q,128]  (h,l*p)
    const float* __restrict__ refp,    // [B,Q,4,2]
    float* __restrict__ outh,          // [B,Q,256]  (h*32+dh)
    float* __restrict__ awout)         // [B,Q,128]
{
    const int t = blockIdx.x * 256 + threadIdx.x;
    if (t >= BQn * QN * NH * 8) return;
    const int lc = t & 7;          // channel chunk / point-pair owner
    const int h  = (t >> 3) & 7;
    const int bq = t >> 6;
    const int b  = bq / QN;
    const int wl = threadIdx.x & 63;       // lane in wave
    const int gbase = wl & 56;             // group base lane (groups aligned)

    // ---- distributed softmax over the 16 logits of (bq,h): 2 per lane ----
    const float2 lw2 = *(const float2*)(awpre + (size_t)bq * 128 + h * 16 + lc * 2);
    float m = fmaxf(lw2.x, lw2.y);
    #pragma unroll
    for (int d = 1; d < 8; d <<= 1) m = fmaxf(m, __shfl_xor(m, d, 8));
    float e0 = expf(lw2.x - m), e1 = expf(lw2.y - m);
    float s = e0 + e1;
    #pragma unroll
    for (int d = 1; d < 8; d <<= 1) s += __shfl_xor(s, d, 8);
    const float inv = 1.f / s;
    e0 *= inv; e1 *= inv;
    *(float2*)(awout + (size_t)bq * 128 + h * 16 + lc * 2) = make_float2(e0, e1);

    // ---- this lane's two points: offsets + reference point ----
    const float4 o4 = *(const float4*)(off + (size_t)bq * 256 + h * 32 + lc * 4);
    const int lvl = lc >> 1;               // level of both owned points
    const float2 rp = *(const float2*)(refp + (size_t)bq * 8 + lvl * 2);
    // level dims via select chain (no runtime-indexed arrays)
    const float fw = (lvl == 0) ? 100.f : (lvl == 1) ? 50.f : (lvl == 2) ? 25.f : 13.f;
    const float lx0 = rp.x + o4.x / fw, ly0 = rp.y + o4.y / fw;
    const float lx1 = rp.x + o4.z / fw, ly1 = rp.y + o4.w / fw;

    float ax = 0.f, ay = 0.f, az = 0.f, aw_ = 0.f;
    const float* vplane = value + (((size_t)b * NH + h) * SN) * DH;

    #pragma unroll
    for (int p = 0; p < 16; ++p) {
        constexpr int LW[4]  = {100, 50, 25, 13};
        constexpr int LST[4] = {0, 10000, 12500, 13125};
        const int l  = p >> 2;
        const int w  = LW[l];        // compile-time (p is unrolled)
        const int hh = LW[l];
        const int st = LST[l];
        const int src = gbase + (p >> 1);
        const float lx = __shfl((p & 1) ? lx1 : lx0, src, 64);
        const float ly = __shfl((p & 1) ? ly1 : ly0, src, 64);
        const float wt = __shfl((p & 1) ? e1  : e0,  src, 64);

        const float x = lx * (float)w - 0.5f;
        const float y = ly * (float)hh - 0.5f;
        const float x0f = floorf(x), y0f = floorf(y);
        const int x0 = (int)x0f, y0 = (int)y0f;
        const float wx1 = x - x0f, wx0 = 1.f - wx1;
        const float wy1 = y - y0f, wy0 = 1.f - wy1;

        const float* vb = vplane + (size_t)st * DH + lc * 4;

        #pragma unroll
        for (int c = 0; c < 4; ++c) {
            const int xi = x0 + (c & 1);
            const int yi = y0 + (c >> 1);
            const float cw = ((c & 1) ? wx1 : wx0) * ((c >> 1) ? wy1 : wy0);
            if (xi >= 0 && xi < w && yi >= 0 && yi < hh) {
                const float wgt = cw * wt;
                const float4 v = *(const float4*)(vb + (size_t)(yi * w + xi) * DH);
                ax = fmaf(wgt, v.x, ax);
                ay = fmaf(wgt, v.y, ay);
                az = fmaf(wgt, v.z, az);
                aw_ = fmaf(wgt, v.w, aw_);
            }
        }
    }

    *(float4*)(outh + (size_t)bq * 256 + h * 32 + lc * 4) =
        make_float4(ax, ay, az, aw_);
}

// ---------------------------------------------------------------------------
extern "C" void kernel_launch(void* const* d_in, const int* in_sizes, int n_in,
                              void* d_out, int out_size, void* d_ws, size_t ws_size,
                              hipStream_t stream) {
    const float* hs   = (const float*)d_in[0];
    const float* enc  = (const float*)d_in[1];
    const float* refp = (const float*)d_in[2];
    const float* Wv   = (const float*)d_in[3];
    const float* bv   = (const float*)d_in[4];
    const float* Woff = (const float*)d_in[5];
    const float* boff = (const float*)d_in[6];
    const float* Wa   = (const float*)d_in[7];
    const float* ba   = (const float*)d_in[8];
    const float* Wout = (const float*)d_in[9];
    const float* bout = (const float*)d_in[10];

    float* out    = (float*)d_out;
    float* aw_out = out + (size_t)BQn * QN * 256;

    float* ws    = (float*)d_ws;
    float* value = ws;                                    // B*H*S*32
    float* offb  = value + (size_t)BQn * NH * SN * DH;    // B*Q*256
    float* awpre = offb  + (size_t)BQn * QN * 256;        // B*Q*128
    float* outh  = awpre + (size_t)BQn * QN * 128;        // B*Q*256

    const int M = BQn * SN;                               // 26588
    const dim3 blk(256);
    const int my = (M + 63) / 64;

    gemm_bias<256, 1><<<dim3(4, my), blk, 0, stream>>>(enc,  Wv,   bv,   value, M);
    gemm_bias<256, 0><<<dim3(4, my), blk, 0, stream>>>(hs,   Woff, boff, offb,  M);
    gemm_bias<128, 0><<<dim3(2, my), blk, 0, stream>>>(hs,   Wa,   ba,   awpre, M);

    const int nt = BQn * QN * NH * 8;
    ms_sample<<<(nt + 255) / 256, blk, 0, stream>>>(value, offb, awpre, refp,
                                                    outh, aw_out);

    gemm_bias<256, 0><<<dim3(4, my), blk, 0, stream>>>(outh, Wout, bout, out, M);
}

// Round 3
// 192.618 us; speedup vs baseline: 2.2754x; 1.6007x over previous
//
#include <hip/hip_runtime.h>
#include <math.h>

#define BQn 2
#define QN 13294
#define SN 13294
#define NH 8
#define DH 32
#define DM 256

typedef __attribute__((ext_vector_type(8))) short short8;
typedef __attribute__((ext_vector_type(4))) float f32x4;

__device__ __forceinline__ unsigned short f2bf(float x) {
    union { float f; unsigned int u; } c; c.f = x;
    unsigned int r = c.u + 0x7fff + ((c.u >> 16) & 1);   // RNE
    return (unsigned short)(r >> 16);
}

// ---------------------------------------------------------------------------
// fp32 -> bf16 row-major conversion (4 elems/thread)
// ---------------------------------------------------------------------------
__global__ __launch_bounds__(256) void conv_bf16(
    const float* __restrict__ in, unsigned short* __restrict__ out, int n)
{
    const int i = (blockIdx.x * 256 + threadIdx.x) * 4;
    if (i >= n) return;
    const float4 v = *(const float4*)(in + i);
    ushort4 o;
    o.x = f2bf(v.x); o.y = f2bf(v.y); o.z = f2bf(v.z); o.w = f2bf(v.w);
    *(ushort4*)(out + i) = o;
}

// W [256][N] fp32 -> WT [N][256] bf16
template<int N>
__global__ __launch_bounds__(256) void convWT(
    const float* __restrict__ W, unsigned short* __restrict__ WT)
{
    const int t = blockIdx.x * 256 + threadIdx.x;
    if (t >= N * 256) return;
    const int n = t % N, k = t / N;
    WT[(size_t)n * 256 + k] = f2bf(W[(size_t)k * N + n]);
}

// ---------------------------------------------------------------------------
// bf16 MFMA GEMM: C[M,N] = A[M,256] @ WT[N,256]^T + bias[N]
// 128x64 tile, 4 waves (2x2), each wave 64x32 via 4x2 16x16x32 fragments.
// MODE 0: row-major C[M,N]; MODE 1: value layout C[b][h][s][dh].
// ---------------------------------------------------------------------------
template<int N, int MODE>
__global__ __launch_bounds__(256) void gemm_mfma(
    const unsigned short* __restrict__ A,   // [M][256] bf16
    const unsigned short* __restrict__ WT,  // [N][256] bf16
    const float* __restrict__ bias,         // [N] fp32
    float* __restrict__ C, int M)
{
    __shared__ unsigned short As[128][72];  // +8 pad: 144B stride, 2-way alias (free)
    __shared__ unsigned short Bs[64][72];
    const int tid  = threadIdx.x;
    const int lane = tid & 63, wid = tid >> 6;
    const int wr = wid >> 1, wc = wid & 1;
    const int r0 = blockIdx.y * 128, n0 = blockIdx.x * 64;

    f32x4 acc[4][2] = {};

    for (int k0 = 0; k0 < 256; k0 += 64) {
        #pragma unroll
        for (int i = 0; i < 4; ++i) {           // A tile 128x64
            const int idx = i * 256 + tid;
            const int row = idx >> 3, ch = (idx & 7) << 3;
            int grow = r0 + row; if (grow >= M) grow = M - 1;
            *(uint4*)&As[row][ch] =
                *(const uint4*)(A + (size_t)grow * 256 + k0 + ch);
        }
        #pragma unroll
        for (int i = 0; i < 2; ++i) {           // B tile 64x64 (rows = N cols)
            const int idx = i * 256 + tid;
            const int row = idx >> 3, ch = (idx & 7) << 3;
            *(uint4*)&Bs[row][ch] =
                *(const uint4*)(WT + (size_t)(n0 + row) * 256 + k0 + ch);
        }
        __syncthreads();
        #pragma unroll
        for (int kk = 0; kk < 2; ++kk) {
            const int kb = kk * 32 + (lane >> 4) * 8;
            short8 bfr[2];
            #pragma unroll
            for (int n = 0; n < 2; ++n)
                bfr[n] = *(const short8*)&Bs[wc * 32 + n * 16 + (lane & 15)][kb];
            #pragma unroll
            for (int m = 0; m < 4; ++m) {
                const short8 afr =
                    *(const short8*)&As[wr * 64 + m * 16 + (lane & 15)][kb];
                #pragma unroll
                for (int n = 0; n < 2; ++n)
                    acc[m][n] = __builtin_amdgcn_mfma_f32_16x16x32_bf16(
                        afr, bfr[n], acc[m][n], 0, 0, 0);
            }
        }
        __syncthreads();
    }

    #pragma unroll
    for (int m = 0; m < 4; ++m)
        #pragma unroll
        for (int n = 0; n < 2; ++n) {
            const int col = n0 + wc * 32 + n * 16 + (lane & 15);
            #pragma unroll
            for (int j = 0; j < 4; ++j) {
                const int row = r0 + wr * 64 + m * 16 + (lane >> 4) * 4 + j;
                if (row >= M) continue;
                const float v = acc[m][n][j] + bias[col];
                if (MODE == 0) {
                    C[(size_t)row * N + col] = v;
                } else {
                    const int b = row / SN, s = row - b * SN;
                    const int h = col >> 5, dh = col & 31;
                    C[(((size_t)b * NH + h) * SN + s) * DH + dh] = v;
                }
            }
        }
}

// ---------------------------------------------------------------------------
// Deformable sampling: 8 lanes per (b,q,h); lane lc owns channels
// [4*lc,4*lc+4) and point-pairs 2*lc, 2*lc+1. Coalesced gathers.
// Writes outh in bf16 (feeds the out-projection MFMA GEMM).
// ---------------------------------------------------------------------------
__global__ __launch_bounds__(256) void ms_sample(
    const float* __restrict__ value,          // [B,H,S,32]
    const float* __restrict__ off,            // [B,Q,256]
    const float* __restrict__ awpre,          // [B,Q,128]
    const float* __restrict__ refp,           // [B,Q,4,2]
    unsigned short* __restrict__ outh,        // [B,Q,256] bf16
    float* __restrict__ awout)                // [B,Q,128]
{
    const int t = blockIdx.x * 256 + threadIdx.x;
    if (t >= BQn * QN * NH * 8) return;
    const int lc = t & 7;
    const int h  = (t >> 3) & 7;
    const int bq = t >> 6;
    const int b  = bq / QN;
    const int wl = threadIdx.x & 63;
    const int gbase = wl & 56;

    // distributed softmax over 16 logits: 2 per lane
    const float2 lw2 = *(const float2*)(awpre + (size_t)bq * 128 + h * 16 + lc * 2);
    float m = fmaxf(lw2.x, lw2.y);
    #pragma unroll
    for (int d = 1; d < 8; d <<= 1) m = fmaxf(m, __shfl_xor(m, d, 8));
    float e0 = expf(lw2.x - m), e1 = expf(lw2.y - m);
    float s = e0 + e1;
    #pragma unroll
    for (int d = 1; d < 8; d <<= 1) s += __shfl_xor(s, d, 8);
    const float inv = 1.f / s;
    e0 *= inv; e1 *= inv;
    *(float2*)(awout + (size_t)bq * 128 + h * 16 + lc * 2) = make_float2(e0, e1);

    // this lane's two points
    const float4 o4 = *(const float4*)(off + (size_t)bq * 256 + h * 32 + lc * 4);
    const int lvl = lc >> 1;
    const float2 rp = *(const float2*)(refp + (size_t)bq * 8 + lvl * 2);
    const float fw = (lvl == 0) ? 100.f : (lvl == 1) ? 50.f : (lvl == 2) ? 25.f : 13.f;
    const float lx0 = rp.x + o4.x / fw, ly0 = rp.y + o4.y / fw;
    const float lx1 = rp.x + o4.z / fw, ly1 = rp.y + o4.w / fw;

    float ax = 0.f, ay = 0.f, az = 0.f, aw_ = 0.f;
    const float* vplane = value + (((size_t)b * NH + h) * SN) * DH;

    #pragma unroll
    for (int p = 0; p < 16; ++p) {
        constexpr int LW[4]  = {100, 50, 25, 13};
        constexpr int LST[4] = {0, 10000, 12500, 13125};
        const int l  = p >> 2;
        const int w  = LW[l];
        const int hh = LW[l];
        const int st = LST[l];
        const int src = gbase + (p >> 1);
        const float lx = __shfl((p & 1) ? lx1 : lx0, src, 64);
        const float ly = __shfl((p & 1) ? ly1 : ly0, src, 64);
        const float wt = __shfl((p & 1) ? e1  : e0,  src, 64);

        const float x = lx * (float)w - 0.5f;
        const float y = ly * (float)hh - 0.5f;
        const float x0f = floorf(x), y0f = floorf(y);
        const int x0 = (int)x0f, y0 = (int)y0f;
        const float wx1 = x - x0f, wx0 = 1.f - wx1;
        const float wy1 = y - y0f, wy0 = 1.f - wy1;

        const float* vb = vplane + (size_t)st * DH + lc * 4;

        #pragma unroll
        for (int c = 0; c < 4; ++c) {
            const int xi = x0 + (c & 1);
            const int yi = y0 + (c >> 1);
            const float cw = ((c & 1) ? wx1 : wx0) * ((c >> 1) ? wy1 : wy0);
            if (xi >= 0 && xi < w && yi >= 0 && yi < hh) {
                const float wgt = cw * wt;
                const float4 v = *(const float4*)(vb + (size_t)(yi * w + xi) * DH);
                ax  = fmaf(wgt, v.x, ax);
                ay  = fmaf(wgt, v.y, ay);
                az  = fmaf(wgt, v.z, az);
                aw_ = fmaf(wgt, v.w, aw_);
            }
        }
    }

    ushort4 o;
    o.x = f2bf(ax); o.y = f2bf(ay); o.z = f2bf(az); o.w = f2bf(aw_);
    *(ushort4*)(outh + (size_t)bq * 256 + h * 32 + lc * 4) = o;
}

// ---------------------------------------------------------------------------
extern "C" void kernel_launch(void* const* d_in, const int* in_sizes, int n_in,
                              void* d_out, int out_size, void* d_ws, size_t ws_size,
                              hipStream_t stream) {
    const float* hs   = (const float*)d_in[0];
    const float* enc  = (const float*)d_in[1];
    const float* refp = (const float*)d_in[2];
    const float* Wv   = (const float*)d_in[3];
    const float* bv   = (const float*)d_in[4];
    const float* Woff = (const float*)d_in[5];
    const float* boff = (const float*)d_in[6];
    const float* Wa   = (const float*)d_in[7];
    const float* ba   = (const float*)d_in[8];
    const float* Wout = (const float*)d_in[9];
    const float* bout = (const float*)d_in[10];

    float* out    = (float*)d_out;
    float* aw_out = out + (size_t)BQn * QN * 256;

    const size_t MQ = (size_t)BQn * QN;      // 26588
    float* ws    = (float*)d_ws;
    float* value = ws;                        // MQ*256 f32 (as [B,H,S,32])
    float* offb  = value + MQ * 256;          // MQ*256 f32
    float* awpre = offb  + MQ * 256;          // MQ*128 f32
    unsigned short* encb = (unsigned short*)(awpre + MQ * 128);  // MQ*256 bf16
    unsigned short* hsb  = encb + MQ * 256;                      // MQ*256 bf16
    unsigned short* WvT  = hsb + MQ * 256;    // 256*256
    unsigned short* WoffT = WvT  + 256 * 256; // 256*256
    unsigned short* WaT   = WoffT + 256 * 256;// 128*256
    unsigned short* WoutT = WaT  + 128 * 256; // 256*256
    unsigned short* outhb = encb;             // alias: encb dead after value GEMM

    const int M = (int)MQ;
    const dim3 blk(256);
    const int nA = M * 256;
    const int cgrid = (nA / 4 + 255) / 256;

    conv_bf16<<<cgrid, blk, 0, stream>>>(enc, encb, nA);
    conv_bf16<<<cgrid, blk, 0, stream>>>(hs,  hsb,  nA);
    convWT<256><<<256, blk, 0, stream>>>(Wv,   WvT);
    convWT<256><<<256, blk, 0, stream>>>(Woff, WoffT);
    convWT<128><<<128, blk, 0, stream>>>(Wa,   WaT);
    convWT<256><<<256, blk, 0, stream>>>(Wout, WoutT);

    const int my = (M + 127) / 128;           // 208
    gemm_mfma<256, 1><<<dim3(4, my), blk, 0, stream>>>(encb, WvT,   bv,   value, M);
    gemm_mfma<256, 0><<<dim3(4, my), blk, 0, stream>>>(hsb,  WoffT, boff, offb,  M);
    gemm_mfma<128, 0><<<dim3(2, my), blk, 0, stream>>>(hsb,  WaT,   ba,   awpre, M);

    const int nt = BQn * QN * NH * 8;
    ms_sample<<<(nt + 255) / 256, blk, 0, stream>>>(value, offb, awpre, refp,
                                                    outhb, aw_out);

    gemm_mfma<256, 0><<<dim3(4, my), blk, 0, stream>>>(outhb, WoutT, bout, out, M);
}

// Round 5
// 159.861 us; speedup vs baseline: 2.7416x; 1.2049x over previous
//
#include <hip/hip_runtime.h>
#include <math.h>

#define BQn 2
#define QN 13294
#define SN 13294
#define NH 8
#define DH 32
#define DM 256

typedef __attribute__((ext_vector_type(8))) short short8;
typedef __attribute__((ext_vector_type(4))) float f32x4;

__device__ __forceinline__ unsigned short f2bf(float x) {
    union { float f; unsigned int u; } c; c.f = x;
    unsigned int r = c.u + 0x7fff + ((c.u >> 16) & 1);   // RNE
    return (unsigned short)(r >> 16);
}
__device__ __forceinline__ float bf2f(unsigned short u) {
    union { unsigned int i; float f; } c; c.i = ((unsigned int)u) << 16;
    return c.f;
}

// ---------------------------------------------------------------------------
// fp32 -> bf16 row-major conversion (4 elems/thread)
// ---------------------------------------------------------------------------
__global__ __launch_bounds__(256) void conv_x(
    const float* __restrict__ in, unsigned short* __restrict__ out, int n)
{
    const int i = (blockIdx.x * 256 + threadIdx.x) * 4;
    if (i >= n) return;
    const float4 v = *(const float4*)(in + i);
    ushort4 o;
    o.x = f2bf(v.x); o.y = f2bf(v.y); o.z = f2bf(v.z); o.w = f2bf(v.w);
    *(ushort4*)(out + i) = o;
}

// ---------------------------------------------------------------------------
// Fused transpose+bf16 of all four weight matrices: W[K][N] -> WT[N][K]
// ---------------------------------------------------------------------------
__global__ __launch_bounds__(256) void conv_weights(
    const float* __restrict__ Wv, const float* __restrict__ Woff,
    const float* __restrict__ Wa, const float* __restrict__ Wout,
    unsigned short* __restrict__ WvT, unsigned short* __restrict__ WoffT,
    unsigned short* __restrict__ WaT, unsigned short* __restrict__ WoutT)
{
    const int t = blockIdx.x * 256 + threadIdx.x;
    if (t < 65536) {
        const int n = t & 255, k = t >> 8;
        WvT[(size_t)n * 256 + k] = f2bf(Wv[(size_t)k * 256 + n]);
    } else if (t < 131072) {
        const int i = t - 65536, n = i & 255, k = i >> 8;
        WoffT[(size_t)n * 256 + k] = f2bf(Woff[(size_t)k * 256 + n]);
    } else if (t < 163840) {
        const int i = t - 131072, n = i & 127, k = i >> 7;
        WaT[(size_t)n * 256 + k] = f2bf(Wa[(size_t)k * 128 + n]);
    } else if (t < 229376) {
        const int i = t - 163840, n = i & 255, k = i >> 8;
        WoutT[(size_t)n * 256 + k] = f2bf(Wout[(size_t)k * 256 + n]);
    }
}

// ---------------------------------------------------------------------------
// bf16 MFMA GEMM: C[M,N] = A[M,256] @ WT[N,256]^T + bias[N]
// 128x64 tile, 4 waves (2x2), each wave 64x32 via 4x2 16x16x32 fragments.
// MODE 0: fp32 row-major C[M,N]; MODE 1: bf16 value layout C[b][h][s][dh].
// ---------------------------------------------------------------------------
template<int N, int MODE>
__global__ __launch_bounds__(256) void gemm_mfma(
    const unsigned short* __restrict__ A,   // [M][256] bf16
    const unsigned short* __restrict__ WT,  // [N][256] bf16
    const float* __restrict__ bias,         // [N] fp32
    void* __restrict__ Cv, int M)
{
    __shared__ unsigned short As[128][72];  // +8 pad: 2-way alias only (free)
    __shared__ unsigned short Bs[64][72];
    const int tid  = threadIdx.x;
    const int lane = tid & 63, wid = tid >> 6;
    const int wr = wid >> 1, wc = wid & 1;
    const int r0 = blockIdx.y * 128, n0 = blockIdx.x * 64;

    f32x4 acc[4][2] = {};

    for (int k0 = 0; k0 < 256; k0 += 64) {
        #pragma unroll
        for (int i = 0; i < 4; ++i) {           // A tile 128x64
            const int idx = i * 256 + tid;
            const int row = idx >> 3, ch = (idx & 7) << 3;
            int grow = r0 + row; if (grow >= M) grow = M - 1;
            *(uint4*)&As[row][ch] =
                *(const uint4*)(A + (size_t)grow * 256 + k0 + ch);
        }
        #pragma unroll
        for (int i = 0; i < 2; ++i) {           // B tile 64x64 (rows = N cols)
            const int idx = i * 256 + tid;
            const int row = idx >> 3, ch = (idx & 7) << 3;
            *(uint4*)&Bs[row][ch] =
                *(const uint4*)(WT + (size_t)(n0 + row) * 256 + k0 + ch);
        }
        __syncthreads();
        #pragma unroll
        for (int kk = 0; kk < 2; ++kk) {
            const int kb = kk * 32 + (lane >> 4) * 8;
            short8 bfr[2];
            #pragma unroll
            for (int n = 0; n < 2; ++n)
                bfr[n] = *(const short8*)&Bs[wc * 32 + n * 16 + (lane & 15)][kb];
            #pragma unroll
            for (int m = 0; m < 4; ++m) {
                const short8 afr =
                    *(const short8*)&As[wr * 64 + m * 16 + (lane & 15)][kb];
                #pragma unroll
                for (int n = 0; n < 2; ++n)
                    acc[m][n] = __builtin_amdgcn_mfma_f32_16x16x32_bf16(
                        afr, bfr[n], acc[m][n], 0, 0, 0);
            }
        }
        __syncthreads();
    }

    #pragma unroll
    for (int m = 0; m < 4; ++m)
        #pragma unroll
        for (int n = 0; n < 2; ++n) {
            const int col = n0 + wc * 32 + n * 16 + (lane & 15);
            #pragma unroll
            for (int j = 0; j < 4; ++j) {
                const int row = r0 + wr * 64 + m * 16 + (lane >> 4) * 4 + j;
                if (row >= M) continue;
                const float v = acc[m][n][j] + bias[col];
                if (MODE == 0) {
                    ((float*)Cv)[(size_t)row * N + col] = v;
                } else {
                    const int b = row / SN, s = row - b * SN;
                    const int h = col >> 5, dh = col & 31;
                    ((unsigned short*)Cv)
                        [(((size_t)b * NH + h) * SN + s) * DH + dh] = f2bf(v);
                }
            }
        }
}

// ---------------------------------------------------------------------------
// Deformable sampling: block = (head, 32-query chunk); h = blockIdx.x & 7
// so the HW round-robin block->XCD dispatch pins each head's two bf16 value
// planes (2 x 0.85 MB) into one XCD's 4 MB L2. 8 lanes per (b,q,h); lane lc
// owns channels [4lc,4lc+4) and point-pairs 2lc,2lc+1; coalesced 64B gathers.
// ---------------------------------------------------------------------------
__global__ __launch_bounds__(256) void ms_sample(
    const unsigned short* __restrict__ value, // [B,H,S,32] bf16
    const float* __restrict__ off,            // [B,Q,256]
    const float* __restrict__ awpre,          // [B,Q,128]
    const float* __restrict__ refp,           // [B,Q,4,2]
    unsigned short* __restrict__ outh,        // [B,Q,256] bf16 (dedicated)
    float* __restrict__ awout)                // [B,Q,128]
{
    const int h  = blockIdx.x & 7;
    const int qc = blockIdx.x >> 3;
    const int lc = threadIdx.x & 7;
    const int bq = qc * 32 + (threadIdx.x >> 3);
    if (bq >= BQn * QN) return;
    const int b  = bq / QN;
    const int wl = threadIdx.x & 63;
    const int gbase = wl & 56;

    // distributed softmax over 16 logits: 2 per lane
    const float2 lw2 = *(const float2*)(awpre + (size_t)bq * 128 + h * 16 + lc * 2);
    float m = fmaxf(lw2.x, lw2.y);
    #pragma unroll
    for (int d = 1; d < 8; d <<= 1) m = fmaxf(m, __shfl_xor(m, d, 8));
    float e0 = expf(lw2.x - m), e1 = expf(lw2.y - m);
    float s = e0 + e1;
    #pragma unroll
    for (int d = 1; d < 8; d <<= 1) s += __shfl_xor(s, d, 8);
    const float inv = 1.f / s;
    e0 *= inv; e1 *= inv;
    *(float2*)(awout + (size_t)bq * 128 + h * 16 + lc * 2) = make_float2(e0, e1);

    // this lane's two points
    const float4 o4 = *(const float4*)(off + (size_t)bq * 256 + h * 32 + lc * 4);
    const int lvl = lc >> 1;
    const float2 rp = *(const float2*)(refp + (size_t)bq * 8 + lvl * 2);
    const float fw = (lvl == 0) ? 100.f : (lvl == 1) ? 50.f : (lvl == 2) ? 25.f : 13.f;
    const float lx0 = rp.x + o4.x / fw, ly0 = rp.y + o4.y / fw;
    const float lx1 = rp.x + o4.z / fw, ly1 = rp.y + o4.w / fw;

    float ax = 0.f, ay = 0.f, az = 0.f, aw_ = 0.f;
    const unsigned short* vplane = value + (((size_t)b * NH + h) * SN) * DH + lc * 4;

    #pragma unroll
    for (int p = 0; p < 16; ++p) {
        constexpr int LW[4]  = {100, 50, 25, 13};
        constexpr int LST[4] = {0, 10000, 12500, 13125};
        const int l  = p >> 2;
        const int w  = LW[l];
        const int hh = LW[l];
        const int st = LST[l];
        const int src = gbase + (p >> 1);
        const float lx = __shfl((p & 1) ? lx1 : lx0, src, 64);
        const float ly = __shfl((p & 1) ? ly1 : ly0, src, 64);
        const float wt = __shfl((p & 1) ? e1  : e0,  src, 64);

        const float x = lx * (float)w - 0.5f;
        const float y = ly * (float)hh - 0.5f;
        const float x0f = floorf(x), y0f = floorf(y);
        const int x0 = (int)x0f, y0 = (int)y0f;
        const float wx1 = x - x0f, wx0 = 1.f - wx1;
        const float wy1 = y - y0f, wy0 = 1.f - wy1;

        #pragma unroll
        for (int c = 0; c < 4; ++c) {
            const int xi = x0 + (c & 1);
            const int yi = y0 + (c >> 1);
            const float cw = ((c & 1) ? wx1 : wx0) * ((c >> 1) ? wy1 : wy0);
            if (xi >= 0 && xi < w && yi >= 0 && yi < hh) {
                const float wgt = cw * wt;
                const ushort4 v =
                    *(const ushort4*)(vplane + (size_t)(st + yi * w + xi) * DH);
                ax  = fmaf(wgt, bf2f(v.x), ax);
                ay  = fmaf(wgt, bf2f(v.y), ay);
                az  = fmaf(wgt, bf2f(v.z), az);
                aw_ = fmaf(wgt, bf2f(v.w), aw_);
            }
        }
    }

    ushort4 o;
    o.x = f2bf(ax); o.y = f2bf(ay); o.z = f2bf(az); o.w = f2bf(aw_);
    *(ushort4*)(outh + (size_t)bq * 256 + h * 32 + lc * 4) = o;
}

// ---------------------------------------------------------------------------
// Workspace layout (82.1 MB, NO aliasing; every region written by exactly one
// kernel, read only by strictly later kernels in the stream):
//   valueb [MQ*256 bf16] <- gemm value     -> ms_sample
//   offb   [MQ*256 f32 ] <- gemm off       -> ms_sample
//   awpre  [MQ*128 f32 ] <- gemm attn      -> ms_sample
//   xb     [MQ*256 bf16] <- conv_x(enc) -> gemm value; conv_x(hs) -> off/attn
//   outh   [MQ*256 bf16] <- ms_sample      -> gemm out
//   W*T    [bf16 weights]<- conv_weights   -> gemms
// ---------------------------------------------------------------------------
extern "C" void kernel_launch(void* const* d_in, const int* in_sizes, int n_in,
                              void* d_out, int out_size, void* d_ws, size_t ws_size,
                              hipStream_t stream) {
    const float* hs   = (const float*)d_in[0];
    const float* enc  = (const float*)d_in[1];
    const float* refp = (const float*)d_in[2];
    const float* Wv   = (const float*)d_in[3];
    const float* bv   = (const float*)d_in[4];
    const float* Woff = (const float*)d_in[5];
    const float* boff = (const float*)d_in[6];
    const float* Wa   = (const float*)d_in[7];
    const float* ba   = (const float*)d_in[8];
    const float* Wout = (const float*)d_in[9];
    const float* bout = (const float*)d_in[10];

    float* out    = (float*)d_out;
    float* aw_out = out + (size_t)BQn * QN * 256;

    const size_t MQ = (size_t)BQn * QN;      // 26588
    unsigned short* valueb = (unsigned short*)d_ws;              // MQ*256 bf16
    float* offb  = (float*)(valueb + MQ * 256);                  // MQ*256 f32
    float* awpre = offb + MQ * 256;                              // MQ*128 f32
    unsigned short* xb    = (unsigned short*)(awpre + MQ * 128); // MQ*256 bf16
    unsigned short* outh  = xb + MQ * 256;                       // MQ*256 bf16
    unsigned short* WvT   = outh + MQ * 256;                     // 256*256
    unsigned short* WoffT = WvT  + 256 * 256;                    // 256*256
    unsigned short* WaT   = WoffT + 256 * 256;                   // 128*256
    unsigned short* WoutT = WaT  + 128 * 256;                    // 256*256

    const int M = (int)MQ;
    const dim3 blk(256);
    const int nA = M * 256;
    const int cgrid = (nA / 4 + 255) / 256;

    conv_weights<<<896, blk, 0, stream>>>(Wv, Woff, Wa, Wout,
                                          WvT, WoffT, WaT, WoutT);

    const int my = (M + 127) / 128;           // 208
    conv_x<<<cgrid, blk, 0, stream>>>(enc, xb, nA);
    gemm_mfma<256, 1><<<dim3(4, my), blk, 0, stream>>>(xb, WvT,   bv,   valueb, M);
    conv_x<<<cgrid, blk, 0, stream>>>(hs, xb, nA);
    gemm_mfma<256, 0><<<dim3(4, my), blk, 0, stream>>>(xb, WoffT, boff, offb,  M);
    gemm_mfma<128, 0><<<dim3(2, my), blk, 0, stream>>>(xb, WaT,   ba,   awpre, M);

    const int qchunks = (M + 31) / 32;        // 831
    ms_sample<<<8 * qchunks, blk, 0, stream>>>(valueb, offb, awpre, refp,
                                               outh, aw_out);

    gemm_mfma<256, 0><<<dim3(4, my), blk, 0, stream>>>(outh, WoutT, bout, out, M);
}

// Round 6
// 142.792 us; speedup vs baseline: 3.0694x; 1.1195x over previous
//
#include <hip/hip_runtime.h>
#include <hip/hip_bf16.h>
#include <math.h>

#define BQn 2
#define QN 13294
#define SN 13294
#define NH 8
#define DH 32
#define DM 256

typedef __attribute__((ext_vector_type(8))) short short8;
typedef __attribute__((ext_vector_type(4))) float f32x4;

__device__ __forceinline__ unsigned short f2bf(float x) {
    union { float f; unsigned int u; } c; c.f = x;
    unsigned int r = c.u + 0x7fff + ((c.u >> 16) & 1);   // RNE
    return (unsigned short)(r >> 16);
}
__device__ __forceinline__ float asf(unsigned int u) {
    union { unsigned int i; float f; } c; c.i = u; return c.f;
}

// ---------------------------------------------------------------------------
// Fused transpose+bf16 of all four weight matrices: W[K][N] -> WT[N][K]
// WoffT/WaT are adjacent, forming WcatT[384][256] for the merged GEMM.
// ---------------------------------------------------------------------------
__global__ __launch_bounds__(256) void conv_weights(
    const float* __restrict__ Wv, const float* __restrict__ Woff,
    const float* __restrict__ Wa, const float* __restrict__ Wout,
    unsigned short* __restrict__ WvT, unsigned short* __restrict__ WoffT,
    unsigned short* __restrict__ WaT, unsigned short* __restrict__ WoutT)
{
    const int t = blockIdx.x * 256 + threadIdx.x;
    if (t < 65536) {
        const int n = t & 255, k = t >> 8;
        WvT[(size_t)n * 256 + k] = f2bf(Wv[(size_t)k * 256 + n]);
    } else if (t < 131072) {
        const int i = t - 65536, n = i & 255, k = i >> 8;
        WoffT[(size_t)n * 256 + k] = f2bf(Woff[(size_t)k * 256 + n]);
    } else if (t < 163840) {
        const int i = t - 131072, n = i & 127, k = i >> 7;
        WaT[(size_t)n * 256 + k] = f2bf(Wa[(size_t)k * 128 + n]);
    } else if (t < 229376) {
        const int i = t - 163840, n = i & 255, k = i >> 8;
        WoutT[(size_t)n * 256 + k] = f2bf(Wout[(size_t)k * 256 + n]);
    }
}

// ---------------------------------------------------------------------------
// bf16 MFMA GEMM: C[M,N] = A[M,256] @ WT[N,256]^T + bias
// AF32: A is fp32, converted to bf16 in staging (v_cvt_pk_bf16_f32).
// Bias split at col 256: col<256 -> bias0[col], else bias1[col-256].
// MODE 0: fp32 row-major C[M,N]; MODE 1: bf16 value layout C[b][h][s][dh].
// ---------------------------------------------------------------------------
template<int N, int MODE, bool AF32>
__global__ __launch_bounds__(256) void gemm_mfma(
    const void* __restrict__ Av,            // [M][256] fp32 or bf16
    const unsigned short* __restrict__ WT,  // [N][256] bf16
    const float* __restrict__ bias0,        // [min(N,256)] fp32
    const float* __restrict__ bias1,        // [N-256] fp32 (if N>256)
    void* __restrict__ Cv, int M)
{
    __shared__ unsigned short As[128][72];  // +8 pad: 2-way alias only (free)
    __shared__ unsigned short Bs[64][72];
    const int tid  = threadIdx.x;
    const int lane = tid & 63, wid = tid >> 6;
    const int wr = wid >> 1, wc = wid & 1;
    const int r0 = blockIdx.y * 128, n0 = blockIdx.x * 64;

    f32x4 acc[4][2] = {};

    for (int k0 = 0; k0 < 256; k0 += 64) {
        #pragma unroll
        for (int i = 0; i < 4; ++i) {           // A tile 128x64
            const int idx = i * 256 + tid;
            const int row = idx >> 3, ch = (idx & 7) << 3;
            int grow = r0 + row; if (grow >= M) grow = M - 1;
            if (AF32) {
                const float* Af = (const float*)Av;
                const float4 v0 = *(const float4*)(Af + (size_t)grow * 256 + k0 + ch);
                const float4 v1 = *(const float4*)(Af + (size_t)grow * 256 + k0 + ch + 4);
                union { __hip_bfloat162 b[4]; uint4 u; } pk;
                pk.b[0] = __float22bfloat162_rn(make_float2(v0.x, v0.y));
                pk.b[1] = __float22bfloat162_rn(make_float2(v0.z, v0.w));
                pk.b[2] = __float22bfloat162_rn(make_float2(v1.x, v1.y));
                pk.b[3] = __float22bfloat162_rn(make_float2(v1.z, v1.w));
                *(uint4*)&As[row][ch] = pk.u;
            } else {
                const unsigned short* Ab = (const unsigned short*)Av;
                *(uint4*)&As[row][ch] =
                    *(const uint4*)(Ab + (size_t)grow * 256 + k0 + ch);
            }
        }
        #pragma unroll
        for (int i = 0; i < 2; ++i) {           // B tile 64x64 (rows = N cols)
            const int idx = i * 256 + tid;
            const int row = idx >> 3, ch = (idx & 7) << 3;
            *(uint4*)&Bs[row][ch] =
                *(const uint4*)(WT + (size_t)(n0 + row) * 256 + k0 + ch);
        }
        __syncthreads();
        #pragma unroll
        for (int kk = 0; kk < 2; ++kk) {
            const int kb = kk * 32 + (lane >> 4) * 8;
            short8 bfr[2];
            #pragma unroll
            for (int n = 0; n < 2; ++n)
                bfr[n] = *(const short8*)&Bs[wc * 32 + n * 16 + (lane & 15)][kb];
            #pragma unroll
            for (int m = 0; m < 4; ++m) {
                const short8 afr =
                    *(const short8*)&As[wr * 64 + m * 16 + (lane & 15)][kb];
                #pragma unroll
                for (int n = 0; n < 2; ++n)
                    acc[m][n] = __builtin_amdgcn_mfma_f32_16x16x32_bf16(
                        afr, bfr[n], acc[m][n], 0, 0, 0);
            }
        }
        __syncthreads();
    }

    #pragma unroll
    for (int m = 0; m < 4; ++m)
        #pragma unroll
        for (int n = 0; n < 2; ++n) {
            const int col = n0 + wc * 32 + n * 16 + (lane & 15);
            const float bsv = (col < 256) ? bias0[col] : bias1[col - 256];
            #pragma unroll
            for (int j = 0; j < 4; ++j) {
                const int row = r0 + wr * 64 + m * 16 + (lane >> 4) * 4 + j;
                if (row >= M) continue;
                const float v = acc[m][n][j] + bsv;
                if (MODE == 0) {
                    ((float*)Cv)[(size_t)row * N + col] = v;
                } else {
                    const int b = (row >= SN), s = row - b * SN;
                    const int h = col >> 5, dh = col & 31;
                    ((unsigned short*)Cv)
                        [(((size_t)b * NH + h) * SN + s) * DH + dh] = f2bf(v);
                }
            }
        }
}

// ---------------------------------------------------------------------------
// Deformable sampling: block = (head, 32-query chunk); h = blockIdx.x & 7
// pins each head's two bf16 value planes (2 x 0.85 MB) in one XCD's L2.
// 8 lanes per (b,q,h); lane lc owns channels [4lc,4lc+4) and point-pairs
// 2lc,2lc+1. Branchless clamped corners, __expf softmax, 1-op bf16 unpacks.
// Reads offsets+logits from the merged [M][384] activation buffer.
// ---------------------------------------------------------------------------
__global__ __launch_bounds__(256) void ms_sample(
    const unsigned short* __restrict__ value, // [B,H,S,32] bf16
    const float* __restrict__ offaw,          // [B*Q,384] (256 off | 128 logits)
    const float* __restrict__ refp,           // [B,Q,4,2]
    unsigned short* __restrict__ outh,        // [B,Q,256] bf16
    float* __restrict__ awout)                // [B,Q,128]
{
    const int h  = blockIdx.x & 7;
    const int qc = blockIdx.x >> 3;
    const int lc = threadIdx.x & 7;
    const int bq = qc * 32 + (threadIdx.x >> 3);
    if (bq >= BQn * QN) return;
    const int b  = (bq >= QN);
    const int gbase = threadIdx.x & 56;

    const float* rowp = offaw + (size_t)bq * 384;

    // distributed softmax over 16 logits: 2 per lane
    const float2 lw2 = *(const float2*)(rowp + 256 + h * 16 + lc * 2);
    float m = fmaxf(lw2.x, lw2.y);
    #pragma unroll
    for (int d = 1; d < 8; d <<= 1) m = fmaxf(m, __shfl_xor(m, d, 8));
    float e0 = __expf(lw2.x - m), e1 = __expf(lw2.y - m);
    float s = e0 + e1;
    #pragma unroll
    for (int d = 1; d < 8; d <<= 1) s += __shfl_xor(s, d, 8);
    const float inv = 1.f / s;
    e0 *= inv; e1 *= inv;
    *(float2*)(awout + (size_t)bq * 128 + h * 16 + lc * 2) = make_float2(e0, e1);

    // this lane's two points (reciprocal-multiply, fmaf)
    const float4 o4 = *(const float4*)(rowp + h * 32 + lc * 4);
    const int lvl = lc >> 1;
    const float2 rp = *(const float2*)(refp + (size_t)bq * 8 + lvl * 2);
    const float rw = (lvl == 0) ? 0.01f : (lvl == 1) ? 0.02f
                   : (lvl == 2) ? 0.04f : (1.0f / 13.0f);
    const float lx0 = fmaf(o4.x, rw, rp.x), ly0 = fmaf(o4.y, rw, rp.y);
    const float lx1 = fmaf(o4.z, rw, rp.x), ly1 = fmaf(o4.w, rw, rp.y);

    float ax = 0.f, ay = 0.f, az = 0.f, aw_ = 0.f;
    const unsigned short* vplane =
        value + (((size_t)b * NH + h) * SN) * DH + lc * 4;

    #pragma unroll
    for (int p = 0; p < 16; ++p) {
        constexpr int LW[4]  = {100, 50, 25, 13};
        constexpr int LST[4] = {0, 10000, 12500, 13125};
        const int l  = p >> 2;
        const int w  = LW[l];
        const int st = LST[l];
        const int src = gbase + (p >> 1);
        const float lx = __shfl((p & 1) ? lx1 : lx0, src, 64);
        const float ly = __shfl((p & 1) ? ly1 : ly0, src, 64);
        const float wt = __shfl((p & 1) ? e1  : e0,  src, 64);

        const float x = fmaf(lx, (float)w, -0.5f);
        const float y = fmaf(ly, (float)w, -0.5f);
        const float x0f = floorf(x), y0f = floorf(y);
        const int x0 = (int)x0f, y0 = (int)y0f;
        const float wx1 = x - x0f, wx0 = 1.f - wx1;
        const float wy1 = y - y0f, wy0 = 1.f - wy1;

        #pragma unroll
        for (int c = 0; c < 4; ++c) {
            const int xi = x0 + (c & 1);
            const int yi = y0 + (c >> 1);
            const float cw = ((c & 1) ? wx1 : wx0) * ((c >> 1) ? wy1 : wy0);
            const bool valid = ((unsigned)xi < (unsigned)w) &
                               ((unsigned)yi < (unsigned)w);
            const float wgt = valid ? cw * wt : 0.f;
            const int xc = min(max(xi, 0), w - 1);
            const int yc = min(max(yi, 0), w - 1);
            const uint2 v =
                *(const uint2*)(vplane + (size_t)(st + yc * w + xc) * DH);
            ax  = fmaf(wgt, asf(v.x << 16),          ax);
            ay  = fmaf(wgt, asf(v.x & 0xffff0000u),  ay);
            az  = fmaf(wgt, asf(v.y << 16),          az);
            aw_ = fmaf(wgt, asf(v.y & 0xffff0000u),  aw_);
        }
    }

    ushort4 o;
    o.x = f2bf(ax); o.y = f2bf(ay); o.z = f2bf(az); o.w = f2bf(aw_);
    *(ushort4*)(outh + (size_t)bq * 256 + h * 32 + lc * 4) = o;
}

// ---------------------------------------------------------------------------
// Workspace (~68.5 MB, NO aliasing; each region: one producer, later readers):
//   valueb [MQ*256 bf16]  <- gemm value (MODE1, fp32 A=enc)  -> ms_sample
//   offaw  [MQ*384 f32 ]  <- merged off+attn gemm (fp32 A=hs)-> ms_sample
//   outh   [MQ*256 bf16]  <- ms_sample                        -> gemm out
//   WvT/WcatT/WoutT       <- conv_weights                     -> gemms
// ---------------------------------------------------------------------------
extern "C" void kernel_launch(void* const* d_in, const int* in_sizes, int n_in,
                              void* d_out, int out_size, void* d_ws, size_t ws_size,
                              hipStream_t stream) {
    const float* hs   = (const float*)d_in[0];
    const float* enc  = (const float*)d_in[1];
    const float* refp = (const float*)d_in[2];
    const float* Wv   = (const float*)d_in[3];
    const float* bv   = (const float*)d_in[4];
    const float* Woff = (const float*)d_in[5];
    const float* boff = (const float*)d_in[6];
    const float* Wa   = (const float*)d_in[7];
    const float* ba   = (const float*)d_in[8];
    const float* Wout = (const float*)d_in[9];
    const float* bout = (const float*)d_in[10];

    float* out    = (float*)d_out;
    float* aw_out = out + (size_t)BQn * QN * 256;

    const size_t MQ = (size_t)BQn * QN;      // 26588
    unsigned short* valueb = (unsigned short*)d_ws;              // MQ*256 bf16
    float* offaw = (float*)(valueb + MQ * 256);                  // MQ*384 f32
    unsigned short* outh  = (unsigned short*)(offaw + MQ * 384); // MQ*256 bf16
    unsigned short* WvT   = outh + MQ * 256;                     // 256*256
    unsigned short* WcatT = WvT + 256 * 256;                     // 384*256
    unsigned short* WoutT = WcatT + 384 * 256;                   // 256*256

    const int M = (int)MQ;
    const dim3 blk(256);

    conv_weights<<<896, blk, 0, stream>>>(Wv, Woff, Wa, Wout,
                                          WvT, WcatT, WcatT + 65536, WoutT);

    const int my = (M + 127) / 128;           // 208
    gemm_mfma<256, 1, true ><<<dim3(4, my), blk, 0, stream>>>(
        enc, WvT, bv, bv, valueb, M);
    gemm_mfma<384, 0, true ><<<dim3(6, my), blk, 0, stream>>>(
        hs, WcatT, boff, ba, offaw, M);

    const int qchunks = (M + 31) / 32;        // 831
    ms_sample<<<8 * qchunks, blk, 0, stream>>>(valueb, offaw, refp,
                                               outh, aw_out);

    gemm_mfma<256, 0, false><<<dim3(4, my), blk, 0, stream>>>(
        outh, WoutT, bout, bout, out, M);
}